// Round 4
// baseline (196.598 us; speedup 1.0000x reference)
//
#include <hip/hip_runtime.h>
#include <stdint.h>

// B=2, CIN=256, COUT=256, H=W=128, K=3, G=4
#define HW    16384
#define CIN   256
#define COUT  256
#define Hh    128
#define Ww    128
#define OFFC  72        // G*2*K*K

typedef __attribute__((ext_vector_type(4))) float    f32x4;
typedef __attribute__((ext_vector_type(2))) _Float16 f16x2;
typedef __attribute__((ext_vector_type(8))) _Float16 f16x8;
typedef unsigned short u16;
typedef unsigned int   u32;

__device__ __forceinline__ u16 f2h(float f) { return __builtin_bit_cast(u16, (_Float16)f); }
__device__ __forceinline__ u32 pk2(float f) { u32 h = f2h(f); return h | (h << 16); }
__device__ __forceinline__ f16x2 bch(u32 u) { return __builtin_bit_cast(f16x2, u); }

// lgkmcnt-only barrier (minimal form, R3-proven correct): LDS ops retired,
// global loads stay in flight across the barrier.
__device__ __forceinline__ void bar() {
  asm volatile("s_waitcnt lgkmcnt(0)" ::: "memory");
  __builtin_amdgcn_s_barrier();
  asm volatile("" ::: "memory");
}

// ---------------------------------------------------------------------------
// KPREP (R4): transpose path rewritten LDS-free. Thread = (px-quad, ch-chunk):
// 8 coalesced f32x4 row reads (512B/wave-inst), pack to f16 pairs in regs,
// 4 x uint4 stores. No LDS, no __syncthreads, ~28 mem insts/thread total.
// wfrag / wfrag2 branches unchanged.
// ---------------------------------------------------------------------------
__global__ __launch_bounds__(256) void kprep(const float* __restrict__ x, const float* __restrict__ wd,
                                             const float* __restrict__ wo, u16* __restrict__ xt,
                                             u16* __restrict__ wfrag, u16* __restrict__ wfrag2) {
  __shared__ float smem[8 * 576];               // only used by wfrag branch (18 KB)
  int blk = blockIdx.x;
  if (blk < 1024) {                             // ---- transpose to NHWC f16, 128 px ----
    int bg = blk >> 7;
    int p0 = (blk & 127) << 7;
    int pq = threadIdx.x & 31;                  // px quad: px = pq*4 .. +3
    int ck = threadIdx.x >> 5;                  // ch chunk: ch = ck*8 .. +7
    const float* src = x + (size_t)bg * 64 * HW + p0 + pq * 4;
    u32 pk[4][4];                               // [px j][ch pair m]
    #pragma unroll
    for (int m = 0; m < 4; ++m) {
      f32x4 lo = *(const f32x4*)(src + (size_t)(ck * 8 + 2 * m + 0) * HW);
      f32x4 hi = *(const f32x4*)(src + (size_t)(ck * 8 + 2 * m + 1) * HW);
      #pragma unroll
      for (int j = 0; j < 4; ++j)
        pk[j][m] = (u32)f2h(lo[j]) | ((u32)f2h(hi[j]) << 16);
    }
    u16* dst = xt + ((size_t)bg * HW + p0 + pq * 4) * 64 + ck * 8;
    #pragma unroll
    for (int j = 0; j < 4; ++j)
      *(uint4*)(dst + (size_t)j * 64) = make_uint4(pk[j][0], pk[j][1], pk[j][2], pk[j][3]);
  } else if (blk < 1152) {                      // ---- w_deform prepack (8 couts) ----
    int bb = blk - 1024;                        // 0..127
    int nh = bb & 31;                           // couts [nh*8, nh*8+8)
    int g  = bb >> 5;
    const float* src = wd + (size_t)(nh * 8) * 2304 + (size_t)g * 64 * 9;
    #pragma unroll
    for (int r = 0; r < 18; ++r) {
      int idx = threadIdx.x + 256 * r;          // 0..4607
      int cl  = idx / 576;
      int rem = idx - cl * 576;
      smem[cl * 576 + rem] = src[(size_t)cl * 2304 + rem];
    }
    __syncthreads();
    int nt = nh >> 1, nb = (nh & 1) * 8;
    #pragma unroll
    for (int r = 0; r < 18; ++r) {
      int o  = threadIdx.x + 256 * r;           // 0..4607
      int j  = o & 7;
      int n8 = (o >> 3) & 7;
      int q  = (o >> 6) & 3;
      int kcl = o >> 8;                         // t*2+half
      int t = kcl >> 1, half = kcl & 1;
      int cg = half * 32 + q * 8 + j;
      float v = smem[n8 * 576 + cg * 9 + t];
      int kc = (g * 9 + t) * 2 + half;
      int lane = q * 16 + nb + n8;
      wfrag[((size_t)(kc * 16 + nt) * 64 + lane) * 8 + j] = f2h(v);
    }
  } else {                                      // ---- w_offset prepack ----
    int e = (blk - 1152) * 256 + threadIdx.x;   // < 20480
    int j = e & 7;
    int lane = (e >> 3) & 63;
    int idx = e >> 9;
    int kc = idx / 5, nt = idx - 5 * kc;
    int n16 = lane & 15, q = lane >> 4;
    int oc = nt * 16 + n16;
    int c  = kc * 32 + q * 8 + j;
    float v = (oc < OFFC) ? wo[(size_t)oc * CIN + c] : 0.f;
    wfrag2[e] = f2h(v);
  }
}

// ---------------------------------------------------------------------------
// K2 (R4): R0's proven 8-wave structure + full B-frag prefetch + nodrain bar
//   + XCD swizzle. Block = 512 thr, 64 px x 256 cout, 2 blocks/CU.
//   Wave w PRODUCES half-tile (sp=w>>1, hp=w&1); CONSUMES all 8 half-tiles x
//   couts [w*32,w*32+32): acc[4][2]. Per tap: 4 corner gathers (issued one
//   full phase early), bilerp -> LDS, 16 MFMA.
//   NEW: the 4 B-frags of tap t+1 are prefetched during consume(t) into a
//   ping-pong reg set, so consume is pure {ds_read + reg MFMA} -- B L2
//   latency (~300cy, previously serial in every phase) is off the chain.
//   NEW: lgkm-only barrier -- mid-phase gather/B issues never force-drained.
// ---------------------------------------------------------------------------
__device__ __forceinline__ void mkpre(float yy, float xx, int* ob, u32* wp) {
  float y0f = floorf(yy), x0f = floorf(xx);
  float fy = yy - y0f, fx = xx - x0f;
  int y0 = (int)y0f, x0 = (int)x0f;
  int y1 = y0 + 1, x1 = x0 + 1;
  float vy0 = (y0 >= 0 && y0 < Hh) ? 1.f : 0.f;
  float vy1 = (y1 >= 0 && y1 < Hh) ? 1.f : 0.f;
  float vx0 = (x0 >= 0 && x0 < Ww) ? 1.f : 0.f;
  float vx1 = (x1 >= 0 && x1 < Ww) ? 1.f : 0.f;
  wp[0] = pk2((1.f - fy) * (1.f - fx) * vy0 * vx0);   // zero-pad folded into weights
  wp[1] = pk2((1.f - fy) * fx * vy0 * vx1);
  wp[2] = pk2(fy * (1.f - fx) * vy1 * vx0);
  wp[3] = pk2(fy * fx * vy1 * vx1);
  int cy0 = min(max(y0, 0), Hh - 1), cy1 = min(max(y1, 0), Hh - 1);
  int cx0 = min(max(x0, 0), Ww - 1), cx1 = min(max(x1, 0), Ww - 1);
  ob[0] = (cy0 * Ww + cx0) << 7;                // byte offsets, 128 B pixel records
  ob[1] = (cy0 * Ww + cx1) << 7;
  ob[2] = (cy1 * Ww + cx0) << 7;
  ob[3] = (cy1 * Ww + cx1) << 7;
}

__device__ __forceinline__ uint4 bil16(const uint4* v, const u32* wp) {
  f16x2 W0 = bch(wp[0]), W1 = bch(wp[1]), W2 = bch(wp[2]), W3 = bch(wp[3]);
  uint4 r;
  { f16x2 s = bch(v[0].x) * W0 + bch(v[1].x) * W1 + bch(v[2].x) * W2 + bch(v[3].x) * W3; r.x = __builtin_bit_cast(u32, s); }
  { f16x2 s = bch(v[0].y) * W0 + bch(v[1].y) * W1 + bch(v[2].y) * W2 + bch(v[3].y) * W3; r.y = __builtin_bit_cast(u32, s); }
  { f16x2 s = bch(v[0].z) * W0 + bch(v[1].z) * W1 + bch(v[2].z) * W2 + bch(v[3].z) * W3; r.z = __builtin_bit_cast(u32, s); }
  { f16x2 s = bch(v[0].w) * W0 + bch(v[1].w) * W1 + bch(v[2].w) * W2 + bch(v[3].w) * W3; r.w = __builtin_bit_cast(u32, s); }
  return r;
}

__global__ __launch_bounds__(512, 2) void k2(const u16* __restrict__ xt, const u16* __restrict__ wfrag2,
                                             const float* __restrict__ bo, const u16* __restrict__ wfrag,
                                             float* __restrict__ out) {
  __shared__ u16   astage[2 * 8 * 512];         // [buf][s4][h2][lane][8] = 16 KB
  __shared__ float offl[64 * 74];               // [px][oc] stride-74, 18.5 KB
  int tid  = threadIdx.x;
  int lane = tid & 63, n16 = lane & 15, q = (tid >> 4) & 3;
  int wv   = tid >> 6;                          // 0..7
  int sp   = wv >> 1;                           // produced px subtile
  int hp   = wv & 1;                            // produced 32-ch half
  int blk  = blockIdx.x;
  int swz  = (blk & 7) * 64 + (blk >> 3);       // bijective XCD swizzle (512%8==0)
  int b  = swz >> 8;
  int p0 = (swz & 255) << 6;
  int h  = p0 >> 7, w0 = p0 & 127;
  const char* xtb = (const char*)xt + (size_t)b * 4 * HW * 128;
  float fh  = (float)h;
  float fxp = (float)(w0 + sp * 16 + n16);      // producer-pixel x
  int   chb = hp * 64 + q * 16;                 // byte offset within 128 B record
  int   pxl = sp * 16 + n16;

  f32x4 acc[4][2];
  #pragma unroll
  for (int mt = 0; mt < 4; ++mt) {
    acc[mt][0] = (f32x4){0.f, 0.f, 0.f, 0.f};
    acc[mt][1] = (f32x4){0.f, 0.f, 0.f, 0.f};
  }

  // ---- B-frag prologue: tap 0's 4 frags into bfA (overlaps offset conv) ----
  uint4 bfA[4], bfB[4];
  {
    const u16* wb = wfrag + ((size_t)(2 * wv) * 64 + lane) * 8;   // kc=0, nt=2wv
    bfA[0] = *(const uint4*)(wb);
    bfA[1] = *(const uint4*)(wb + 512);
    bfA[2] = *(const uint4*)(wb + 8192);        // kc=1
    bfA[3] = *(const uint4*)(wb + 8704);
  }

  // ---- phase 0: waves 0-3 compute offset conv -> offl ----
  if (wv < 4) {
    f32x4 oacc[5];
    #pragma unroll
    for (int nt = 0; nt < 5; ++nt) {
      int oc = nt * 16 + n16;
      float bv = (oc < OFFC) ? bo[oc] : 0.f;
      oacc[nt] = (f32x4){bv, bv, bv, bv};
    }
    #pragma unroll
    for (int kc = 0; kc < 8; ++kc) {
      int g = kc >> 1;
      f16x8 af = __builtin_bit_cast(f16x8, *(const uint4*)(xtb +
          ((size_t)(g * HW + p0 + wv * 16 + n16)) * 128 + (kc & 1) * 64 + q * 16));
      #pragma unroll
      for (int nt = 0; nt < 5; ++nt) {
        f16x8 bfo = __builtin_bit_cast(f16x8, *(const uint4*)(wfrag2 + (size_t)(((kc * 5 + nt) << 6) + lane) * 8));
        oacc[nt] = __builtin_amdgcn_mfma_f32_16x16x32_f16(af, bfo, oacc[nt], 0, 0, 0);
      }
    }
    #pragma unroll
    for (int nt = 0; nt < 5; ++nt) {
      int oc = nt * 16 + n16;
      if (oc < OFFC) {
        #pragma unroll
        for (int r = 0; r < 4; ++r)
          offl[(wv * 16 + q * 4 + r) * 74 + oc] = oacc[nt][r];
      }
    }
  }
  __syncthreads();                              // offl ready (one-time full drain)

  uint4 dA[4], dB[4];                           // ping-pong gather sets (const-indexed)
  u32   wpA[4], wpB[4];

  auto issue = [&](int gt, uint4* dd, u32* wpp) {
    float oy = offl[pxl * 74 + gt * 2];
    float ox = offl[pxl * 74 + gt * 2 + 1];
    int g = (gt * 57) >> 9;                     // gt/9
    int t = gt - g * 9;
    int i = (t * 683) >> 11;                    // t/3
    int j = t - i * 3;
    int ob[4];
    mkpre(fh + (float)(i - 1) + oy, fxp + (float)(j - 1) + ox, ob, wpp);
    const char* xg = xtb + (size_t)g * HW * 128;
    #pragma unroll
    for (int c = 0; c < 4; ++c)
      dd[c] = *(const uint4*)(xg + ob[c] + chb);
  };
  // consume tap gt from astage[slot] using bfC (tap gt's frags); prefetch
  // tap gt+1's frags into bfN. slot is a literal at each call site.
  auto consume = [&](int slot, int gt, uint4* bfC, uint4* bfN) {
    if (gt < 35) {
      const u16* wb = wfrag + ((size_t)((2 * (gt + 1)) * 16 + 2 * wv) * 64 + lane) * 8;
      bfN[0] = *(const uint4*)(wb);
      bfN[1] = *(const uint4*)(wb + 512);
      bfN[2] = *(const uint4*)(wb + 8192);
      bfN[3] = *(const uint4*)(wb + 8704);
    }
    #pragma unroll
    for (int mt = 0; mt < 4; ++mt) {
      f16x8 af = __builtin_bit_cast(f16x8,
          *(const uint4*)&astage[(slot * 8 + mt * 2 + 0) * 512 + lane * 8]);
      acc[mt][0] = __builtin_amdgcn_mfma_f32_16x16x32_f16(af, __builtin_bit_cast(f16x8, bfC[0]), acc[mt][0], 0, 0, 0);
      acc[mt][1] = __builtin_amdgcn_mfma_f32_16x16x32_f16(af, __builtin_bit_cast(f16x8, bfC[1]), acc[mt][1], 0, 0, 0);
    }
    #pragma unroll
    for (int mt = 0; mt < 4; ++mt) {
      f16x8 af = __builtin_bit_cast(f16x8,
          *(const uint4*)&astage[(slot * 8 + mt * 2 + 1) * 512 + lane * 8]);
      acc[mt][0] = __builtin_amdgcn_mfma_f32_16x16x32_f16(af, __builtin_bit_cast(f16x8, bfC[2]), acc[mt][0], 0, 0, 0);
      acc[mt][1] = __builtin_amdgcn_mfma_f32_16x16x32_f16(af, __builtin_bit_cast(f16x8, bfC[3]), acc[mt][1], 0, 0, 0);
    }
  };

  // ---- prologue: gt=0 -> dA, gt=1 -> dB, produce slot0 from dA ----
  issue(0, dA, wpA);
  issue(1, dB, wpB);
  *(uint4*)&astage[(0 * 8 + sp * 2 + hp) * 512 + lane * 8] = bil16(dA, wpA);
  bar();                                        // slot0 ready; dB + B-prefetch in flight

  // ---- main loop, x2 unrolled: one lgkm-only barrier per tap ----
  #pragma unroll 1
  for (int gt = 0; gt < 36; gt += 2) {
    // even gt: stage tap gt+1 (dB) -> slot1; issue gt+2 -> dA; consume slot0
    *(uint4*)&astage[(1 * 8 + sp * 2 + hp) * 512 + lane * 8] = bil16(dB, wpB);
    if (gt + 2 < 36) issue(gt + 2, dA, wpA);
    consume(0, gt, bfA, bfB);
    bar();
    // odd gt+1: stage tap gt+2 (dA) -> slot0; issue gt+3 -> dB; consume slot1
    if (gt + 2 < 36) {
      *(uint4*)&astage[(0 * 8 + sp * 2 + hp) * 512 + lane * 8] = bil16(dA, wpA);
      issue(gt + 3, dB, wpB);                   // gt+3 <= 35 here (gt <= 32)
    }
    consume(1, gt + 1, bfB, bfA);
    bar();
  }

  // ---- epilogue: px = p0+mt*16+q*4+r, cout = wv*32 + j*16 + n16; ReLU ----
  float* op = out + (size_t)b * COUT * HW + p0;
  #pragma unroll
  for (int mt = 0; mt < 4; ++mt)
    #pragma unroll
    for (int j = 0; j < 2; ++j) {
      f32x4 v = acc[mt][j];
      #pragma unroll
      for (int r = 0; r < 4; ++r) v[r] = fmaxf(v[r], 0.f);
      int cout = wv * 32 + j * 16 + n16;
      *(f32x4*)(op + (size_t)cout * HW + mt * 16 + q * 4) = v;
    }
}

// ---------------------------------------------------------------------------
extern "C" void kernel_launch(void* const* d_in, const int* in_sizes, int n_in,
                              void* d_out, int out_size, void* d_ws, size_t ws_size,
                              hipStream_t stream) {
  const float* x  = (const float*)d_in[0];
  const float* wo = (const float*)d_in[1];
  const float* bo = (const float*)d_in[2];
  const float* wd = (const float*)d_in[3];
  float* out = (float*)d_out;

  // ws: xt 16,777,216 | wfrag 1,179,648 | wfrag2 40,960
  u16* xtp    = (u16*)d_ws;
  u16* wfrag  = (u16*)((char*)d_ws + 16777216);
  u16* wfrag2 = (u16*)((char*)d_ws + 16777216 + 1179648);

  kprep<<<1232, 256, 0, stream>>>(x, wd, wo, xtp, wfrag, wfrag2);
  k2   <<<512,  512, 0, stream>>>(xtp, wfrag2, bo, wfrag, out);
}

// Round 5
// 178.200 us; speedup vs baseline: 1.1032x; 1.1032x over previous
//
#include <hip/hip_runtime.h>
#include <stdint.h>

// B=2, CIN=256, COUT=256, H=W=128, K=3, G=4
#define HW    16384
#define CIN   256
#define COUT  256
#define Hh    128
#define Ww    128
#define OFFC  72        // G*2*K*K

typedef __attribute__((ext_vector_type(4))) float    f32x4;
typedef __attribute__((ext_vector_type(2))) _Float16 f16x2;
typedef __attribute__((ext_vector_type(8))) _Float16 f16x8;
typedef unsigned short u16;
typedef unsigned int   u32;

__device__ __forceinline__ u16 f2h(float f) { return __builtin_bit_cast(u16, (_Float16)f); }
__device__ __forceinline__ u32 pk2(float f) { u32 h = f2h(f); return h | (h << 16); }
__device__ __forceinline__ f16x2 bch(u32 u) { return __builtin_bit_cast(f16x2, u); }

// ---------------------------------------------------------------------------
// KPREP (R5): lean HBM-bound transpose. Tile = 64 px x 64 ch, 2048 blocks.
// Per thread: 4 coalesced f32x4 loads -> pack to 8 u32 (f16 pairs) ->
// 8 ds_write_b32 (skew-rotated cols, 2-way max) -> sync -> 8 ds_read_b32
// (2-way max by 5a+4b mod 32 arithmetic) -> 2 coalesced uint4 stores.
// LDS 9.2 KB, one sync, ~40 insts/thread. Traffic floor ~168 MB ≈ 28-33 us.
// wfrag / wfrag2 branches unchanged (shifted block ranges).
// ---------------------------------------------------------------------------
__global__ __launch_bounds__(256) void kprep(const float* __restrict__ x, const float* __restrict__ wd,
                                             const float* __restrict__ wo, u16* __restrict__ xt,
                                             u16* __restrict__ wfrag, u16* __restrict__ wfrag2) {
  __shared__ float smem[8 * 576];               // 18 KB; transpose uses 9.2 KB as u32
  int blk = blockIdx.x;
  if (blk < 2048) {                             // ---- transpose to NHWC f16, 64 px ----
    int bg = blk >> 8;
    int p0 = (blk & 255) << 6;
    int pq = threadIdx.x & 15;                  // px quad: px = pq*4..+3
    int cs = threadIdx.x >> 4;                  // cpair seed 0..15
    const float* src = x + (size_t)bg * 64 * HW + p0 + pq * 4;
    u32* lds = (u32*)smem;                      // [px][36], col skew-rotated by px
    #pragma unroll
    for (int s = 0; s < 2; ++s) {
      int c2 = cs + 16 * s;                     // cpair index 0..31 (ch 2c2, 2c2+1)
      f32x4 lo = *(const f32x4*)(src + (size_t)(2 * c2 + 0) * HW);
      f32x4 hi = *(const f32x4*)(src + (size_t)(2 * c2 + 1) * HW);
      #pragma unroll
      for (int j = 0; j < 4; ++j) {
        int px = pq * 4 + j;
        u32 pkv = (u32)f2h(lo[j]) | ((u32)f2h(hi[j]) << 16);
        lds[px * 36 + ((c2 + px) & 31)] = pkv;  // skew: bank = 5*px+c2 -> 2-way max
      }
    }
    __syncthreads();
    u16* dstb = xt + ((size_t)bg * HW + p0) * 64;
    #pragma unroll
    for (int r = 0; r < 2; ++r) {
      int e  = r * 256 + threadIdx.x;           // 0..511
      int px = e >> 3, c4 = e & 7;              // cpairs 4c4..4c4+3
      u32 w[4];
      #pragma unroll
      for (int m = 0; m < 4; ++m)
        w[m] = lds[px * 36 + ((4 * c4 + m + px) & 31)];
      *(uint4*)(dstb + (size_t)e * 8) = make_uint4(w[0], w[1], w[2], w[3]);
    }
  } else if (blk < 2176) {                      // ---- w_deform prepack (8 couts) ----
    int bb = blk - 2048;                        // 0..127
    int nh = bb & 31;                           // couts [nh*8, nh*8+8)
    int g  = bb >> 5;
    const float* src = wd + (size_t)(nh * 8) * 2304 + (size_t)g * 64 * 9;
    #pragma unroll
    for (int r = 0; r < 18; ++r) {
      int idx = threadIdx.x + 256 * r;          // 0..4607
      int cl  = idx / 576;
      int rem = idx - cl * 576;
      smem[cl * 576 + rem] = src[(size_t)cl * 2304 + rem];
    }
    __syncthreads();
    int nt = nh >> 1, nb = (nh & 1) * 8;
    #pragma unroll
    for (int r = 0; r < 18; ++r) {
      int o  = threadIdx.x + 256 * r;           // 0..4607
      int j  = o & 7;
      int n8 = (o >> 3) & 7;
      int q  = (o >> 6) & 3;
      int kcl = o >> 8;                         // t*2+half
      int t = kcl >> 1, half = kcl & 1;
      int cg = half * 32 + q * 8 + j;
      float v = smem[n8 * 576 + cg * 9 + t];
      int kc = (g * 9 + t) * 2 + half;
      int lane = q * 16 + nb + n8;
      wfrag[((size_t)(kc * 16 + nt) * 64 + lane) * 8 + j] = f2h(v);
    }
  } else {                                      // ---- w_offset prepack ----
    int e = (blk - 2176) * 256 + threadIdx.x;   // < 20480
    int j = e & 7;
    int lane = (e >> 3) & 63;
    int idx = e >> 9;
    int kc = idx / 5, nt = idx - 5 * kc;
    int n16 = lane & 15, q = lane >> 4;
    int oc = nt * 16 + n16;
    int c  = kc * 32 + q * 8 + j;
    float v = (oc < OFFC) ? wo[(size_t)oc * CIN + c] : 0.f;
    wfrag2[e] = f2h(v);
  }
}

// ---------------------------------------------------------------------------
// K2 (R5): EXACT revert to the proven R0 structure (104.8 us, 64 VGPR,
// __syncthreads barriers, bf1-in-consume, dA/dB ping-pong) + the one
// verified-harmless addition: bijective XCD blockIdx swizzle (FETCH -2.4x).
// Nodrain barriers / setprio / B-prefetch all measured-regressive (R1-R4).
// ---------------------------------------------------------------------------
__device__ __forceinline__ void mkpre(float yy, float xx, int* ob, u32* wp) {
  float y0f = floorf(yy), x0f = floorf(xx);
  float fy = yy - y0f, fx = xx - x0f;
  int y0 = (int)y0f, x0 = (int)x0f;
  int y1 = y0 + 1, x1 = x0 + 1;
  float vy0 = (y0 >= 0 && y0 < Hh) ? 1.f : 0.f;
  float vy1 = (y1 >= 0 && y1 < Hh) ? 1.f : 0.f;
  float vx0 = (x0 >= 0 && x0 < Ww) ? 1.f : 0.f;
  float vx1 = (x1 >= 0 && x1 < Ww) ? 1.f : 0.f;
  wp[0] = pk2((1.f - fy) * (1.f - fx) * vy0 * vx0);   // zero-pad folded into weights
  wp[1] = pk2((1.f - fy) * fx * vy0 * vx1);
  wp[2] = pk2(fy * (1.f - fx) * vy1 * vx0);
  wp[3] = pk2(fy * fx * vy1 * vx1);
  int cy0 = min(max(y0, 0), Hh - 1), cy1 = min(max(y1, 0), Hh - 1);
  int cx0 = min(max(x0, 0), Ww - 1), cx1 = min(max(x1, 0), Ww - 1);
  ob[0] = (cy0 * Ww + cx0) << 7;                // byte offsets, 128 B pixel records
  ob[1] = (cy0 * Ww + cx1) << 7;
  ob[2] = (cy1 * Ww + cx0) << 7;
  ob[3] = (cy1 * Ww + cx1) << 7;
}

__device__ __forceinline__ uint4 bil16(const uint4* v, const u32* wp) {
  f16x2 W0 = bch(wp[0]), W1 = bch(wp[1]), W2 = bch(wp[2]), W3 = bch(wp[3]);
  uint4 r;
  { f16x2 s = bch(v[0].x) * W0 + bch(v[1].x) * W1 + bch(v[2].x) * W2 + bch(v[3].x) * W3; r.x = __builtin_bit_cast(u32, s); }
  { f16x2 s = bch(v[0].y) * W0 + bch(v[1].y) * W1 + bch(v[2].y) * W2 + bch(v[3].y) * W3; r.y = __builtin_bit_cast(u32, s); }
  { f16x2 s = bch(v[0].z) * W0 + bch(v[1].z) * W1 + bch(v[2].z) * W2 + bch(v[3].z) * W3; r.z = __builtin_bit_cast(u32, s); }
  { f16x2 s = bch(v[0].w) * W0 + bch(v[1].w) * W1 + bch(v[2].w) * W2 + bch(v[3].w) * W3; r.w = __builtin_bit_cast(u32, s); }
  return r;
}

__global__ __launch_bounds__(512) void k2(const u16* __restrict__ xt, const u16* __restrict__ wfrag2,
                                          const float* __restrict__ bo, const u16* __restrict__ wfrag,
                                          float* __restrict__ out) {
  __shared__ u16   astage[2 * 8 * 512];         // [buf][s4][h2][lane][8] = 16 KB
  __shared__ float offl[64 * 74];               // [px][oc] stride-74, 18.5 KB
  int tid  = threadIdx.x;
  int lane = tid & 63, n16 = lane & 15, q = (tid >> 4) & 3;
  int wv   = tid >> 6;                          // 0..7
  int sp   = wv >> 1;                           // produced px subtile
  int hp   = wv & 1;                            // produced 32-ch half
  int blk  = blockIdx.x;
  int swz  = (blk & 7) * 64 + (blk >> 3);       // bijective XCD swizzle (512%8==0)
  int b  = swz >> 8;
  int p0 = (swz & 255) << 6;
  int h  = p0 >> 7, w0 = p0 & 127;
  const char* xtb = (const char*)xt + (size_t)b * 4 * HW * 128;
  float fh  = (float)h;
  float fxp = (float)(w0 + sp * 16 + n16);      // producer-pixel x
  int   chb = hp * 64 + q * 16;                 // byte offset within 128 B record

  f32x4 acc[4][2];
  #pragma unroll
  for (int mt = 0; mt < 4; ++mt) {
    acc[mt][0] = (f32x4){0.f, 0.f, 0.f, 0.f};
    acc[mt][1] = (f32x4){0.f, 0.f, 0.f, 0.f};
  }

  // ---- phase 0: waves 0-3 compute offset conv -> offl ----
  if (wv < 4) {
    f32x4 oacc[5];
    #pragma unroll
    for (int nt = 0; nt < 5; ++nt) {
      int oc = nt * 16 + n16;
      float bv = (oc < OFFC) ? bo[oc] : 0.f;
      oacc[nt] = (f32x4){bv, bv, bv, bv};
    }
    #pragma unroll
    for (int kc = 0; kc < 8; ++kc) {
      int g = kc >> 1;
      f16x8 af = __builtin_bit_cast(f16x8, *(const uint4*)(xtb +
          ((size_t)(g * HW + p0 + wv * 16 + n16)) * 128 + (kc & 1) * 64 + q * 16));
      #pragma unroll
      for (int nt = 0; nt < 5; ++nt) {
        f16x8 bfo = __builtin_bit_cast(f16x8, *(const uint4*)(wfrag2 + (size_t)(((kc * 5 + nt) << 6) + lane) * 8));
        oacc[nt] = __builtin_amdgcn_mfma_f32_16x16x32_f16(af, bfo, oacc[nt], 0, 0, 0);
      }
    }
    #pragma unroll
    for (int nt = 0; nt < 5; ++nt) {
      int oc = nt * 16 + n16;
      if (oc < OFFC) {
        #pragma unroll
        for (int r = 0; r < 4; ++r)
          offl[(wv * 16 + q * 4 + r) * 74 + oc] = oacc[nt][r];
      }
    }
  }
  uint4 bf0[2];                                 // persistent hh=0 B-frags (slice wv)
  bf0[0] = *(const uint4*)(wfrag + ((size_t)(wv * 2 + 0) * 64 + lane) * 8);
  bf0[1] = *(const uint4*)(wfrag + ((size_t)(wv * 2 + 1) * 64 + lane) * 8);
  __syncthreads();                              // offl ready

  uint4 dA[4], dB[4];                           // ping-pong gather sets (const-indexed!)
  u32   wpA[4], wpB[4];

  auto issue = [&](int gt, uint4* dd, u32* wpp) {
    int pxl = sp * 16 + n16;
    float oy = offl[pxl * 74 + gt * 2];
    float ox = offl[pxl * 74 + gt * 2 + 1];
    int g = (gt * 57) >> 9;                     // gt/9
    int t = gt - g * 9;
    int i = (t * 683) >> 11;                    // t/3
    int j = t - i * 3;
    int ob[4];
    mkpre(fh + (float)(i - 1) + oy, fxp + (float)(j - 1) + ox, ob, wpp);
    const char* xg = xtb + (size_t)g * HW * 128;
    #pragma unroll
    for (int c = 0; c < 4; ++c)
      dd[c] = *(const uint4*)(xg + ob[c] + chb);
  };
  auto consume = [&](int slot, int gt) {        // slot passed as constant
    uint4 bf1[2];
    const u16* wb1 = wfrag + ((size_t)((2 * gt + 1) * 16 + wv * 2) * 64 + lane) * 8;
    bf1[0] = *(const uint4*)(wb1);
    bf1[1] = *(const uint4*)(wb1 + 512);
    #pragma unroll
    for (int mt = 0; mt < 4; ++mt) {
      f16x8 af = __builtin_bit_cast(f16x8,
          *(const uint4*)&astage[(slot * 8 + mt * 2 + 0) * 512 + lane * 8]);
      acc[mt][0] = __builtin_amdgcn_mfma_f32_16x16x32_f16(af, __builtin_bit_cast(f16x8, bf0[0]), acc[mt][0], 0, 0, 0);
      acc[mt][1] = __builtin_amdgcn_mfma_f32_16x16x32_f16(af, __builtin_bit_cast(f16x8, bf0[1]), acc[mt][1], 0, 0, 0);
    }
    #pragma unroll
    for (int mt = 0; mt < 4; ++mt) {
      f16x8 af = __builtin_bit_cast(f16x8,
          *(const uint4*)&astage[(slot * 8 + mt * 2 + 1) * 512 + lane * 8]);
      acc[mt][0] = __builtin_amdgcn_mfma_f32_16x16x32_f16(af, __builtin_bit_cast(f16x8, bf1[0]), acc[mt][0], 0, 0, 0);
      acc[mt][1] = __builtin_amdgcn_mfma_f32_16x16x32_f16(af, __builtin_bit_cast(f16x8, bf1[1]), acc[mt][1], 0, 0, 0);
    }
    if (gt < 35) {                              // prefetch hh=0 B of gt+1
      const u16* wb0 = wfrag + ((size_t)((2 * gt + 2) * 16 + wv * 2) * 64 + lane) * 8;
      bf0[0] = *(const uint4*)(wb0);
      bf0[1] = *(const uint4*)(wb0 + 512);
    }
  };

  // ---- prologue: gt=0 -> dA, gt=1 -> dB, produce slot0 from dA ----
  issue(0, dA, wpA);
  issue(1, dB, wpB);
  *(uint4*)&astage[(0 * 8 + sp * 2 + hp) * 512 + lane * 8] = bil16(dA, wpA);
  __syncthreads();                              // slot0 ready

  // ---- main loop, x2 unrolled: one barrier per gt, all indices constant ----
  #pragma unroll 1
  for (int gt = 0; gt < 36; gt += 2) {
    // even gt: consume slot0; produce gt+1 (dB) -> slot1; issue gt+2 -> dA
    *(uint4*)&astage[(1 * 8 + sp * 2 + hp) * 512 + lane * 8] = bil16(dB, wpB);
    if (gt + 2 < 36) issue(gt + 2, dA, wpA);
    consume(0, gt);
    __syncthreads();
    // odd gt+1: consume slot1; produce gt+2 (dA) -> slot0; issue gt+3 -> dB
    if (gt + 2 < 36) {
      *(uint4*)&astage[(0 * 8 + sp * 2 + hp) * 512 + lane * 8] = bil16(dA, wpA);
      issue(gt + 3, dB, wpB);                   // gt+3 == 36 never reached (gt<34 here)
    }
    consume(1, gt + 1);
    __syncthreads();
  }

  // ---- epilogue: px = p0+mt*16+q*4+r, cout = wv*32 + j*16 + n16; ReLU ----
  float* op = out + (size_t)b * COUT * HW + p0;
  #pragma unroll
  for (int mt = 0; mt < 4; ++mt)
    #pragma unroll
    for (int j = 0; j < 2; ++j) {
      f32x4 v = acc[mt][j];
      #pragma unroll
      for (int r = 0; r < 4; ++r) v[r] = fmaxf(v[r], 0.f);
      int cout = wv * 32 + j * 16 + n16;
      *(f32x4*)(op + (size_t)cout * HW + mt * 16 + q * 4) = v;
    }
}

// ---------------------------------------------------------------------------
extern "C" void kernel_launch(void* const* d_in, const int* in_sizes, int n_in,
                              void* d_out, int out_size, void* d_ws, size_t ws_size,
                              hipStream_t stream) {
  const float* x  = (const float*)d_in[0];
  const float* wo = (const float*)d_in[1];
  const float* bo = (const float*)d_in[2];
  const float* wd = (const float*)d_in[3];
  float* out = (float*)d_out;

  // ws: xt 16,777,216 | wfrag 1,179,648 | wfrag2 40,960
  u16* xtp    = (u16*)d_ws;
  u16* wfrag  = (u16*)((char*)d_ws + 16777216);
  u16* wfrag2 = (u16*)((char*)d_ws + 16777216 + 1179648);

  kprep<<<2256, 256, 0, stream>>>(x, wd, wo, xtp, wfrag, wfrag2);
  k2   <<<512,  512, 0, stream>>>(xtp, wfrag2, bo, wfrag, out);
}